// Round 14
// baseline (60.768 us; speedup 1.0000x reference)
//
#include <hip/hip_runtime.h>
#include <math.h>

#define INDIM 10
#define DIM 32
#define LAYERS 4
#define MODES 17

#define LOG2E 1.4426950408889634f
#define LN2   0.6931471805599453f

// d_ws layout:
//   [0, 11264)        : frag f16 [11][64][8]  (A-operand fragments, W^T form)
//   [11264, 12032)    : bias2 f32 [6][32]     (compact per-stage bias tables)
#define WS_FRAG_OFF 0
#define WS_BIAS_OFF 11264

typedef _Float16 f16;
typedef _Float16 f16x8 __attribute__((ext_vector_type(8)));
typedef float f32x16 __attribute__((ext_vector_type(16)));
typedef unsigned u32x2 __attribute__((ext_vector_type(2)));

union BU { f16x8 v; unsigned u[4]; };
union CU { f32x16 v; float4 q[4]; };

// ---------------------------------------------------------------------------
// FUSED prep (round-13-verified): folds rfft -> mode-mix -> irfft into
// Wc[l] = M_l + proj_W[l], writes f16 A-fragments directly, block 0 packs
// stem/head fragments and bias tables.  log2e folding verified round 11.
// ---------------------------------------------------------------------------
__global__ void fno_prep(const float* __restrict__ wr,
                         const float* __restrict__ wi,
                         const float* __restrict__ projW,
                         const float* __restrict__ stemW,
                         const float* __restrict__ headW,
                         const float* __restrict__ stemB,
                         const float* __restrict__ projB,
                         const float* __restrict__ headB,
                         f16* __restrict__ frag,
                         float* __restrict__ bias2) {
    const int l  = blockIdx.x;
    const int tx = threadIdx.x;
    const int j  = tx & 31;   // output position n' (= frag column c)
    const int n  = tx >> 5;   // input position n  (= frag k)

    __shared__ float ct[32], st[32];
    if (tx < 32) {
        float ang = (2.0f * 3.14159265358979323846f / 32.0f) * (float)tx;
        ct[tx] = cosf(ang);
        st[tx] = sinf(ang);
    }
    __syncthreads();

    const float* lwr = wr + l * MODES * MODES;
    const float* lwi = wi + l * MODES * MODES;

    float acc = 0.0f;
    for (int o = 0; o < MODES; ++o) {
        float re = 0.0f, im = 0.0f;
        for (int m = 0; m < MODES; ++m) {
            int t = (m * n) & 31;
            float c = ct[t], s = st[t];
            float a = lwr[m * MODES + o];
            float b = lwi[m * MODES + o];
            re += c * a + s * b;
            im += c * b - s * a;
        }
        int t2 = (o * j) & 31;
        float f = (o == 0 || o == 16) ? 1.0f : 2.0f;
        acc += f * (re * ct[t2] - im * st[t2]);
    }
    acc = acc * (1.0f / 32.0f) + projW[(l * DIM + n) * DIM + j];

    const float wscale = (l == 0) ? LOG2E : 1.0f;
    const int kc = n >> 4;
    const int G  = (n >> 3) & 1;
    const int e  = n & 7;
    const int ln = G * 32 + j;
    frag[((l * 2 + kc) * 64 + ln) * 8 + e] = (f16)(wscale * acc);

    if (l == 0) {
        if (tx < 64) {
            const int lnn = tx;
            const int c2  = lnn & 31;
            const int G2  = lnn >> 5;
#pragma unroll
            for (int ee = 0; ee < 8; ++ee) {
                int k = 8 * G2 + ee;
                frag[(8 * 64 + lnn) * 8 + ee] =
                    (f16)(k < INDIM ? stemW[k * DIM + c2] : 0.0f);
            }
#pragma unroll
            for (int kcc = 0; kcc < 2; ++kcc)
#pragma unroll
                for (int ee = 0; ee < 8; ++ee) {
                    int k = 16 * kcc + 8 * G2 + ee;
                    frag[((9 + kcc) * 64 + lnn) * 8 + ee] =
                        (f16)(c2 < INDIM ? LN2 * headW[k * INDIM + c2] : 0.0f);
                }
        }
        if (tx < 32) {
#pragma unroll
            for (int f = 0; f < 6; ++f) {
                float v;
                if (f == 0)      v = stemB[tx];
                else if (f <= 4) v = LOG2E * projB[(f - 1) * DIM + tx];
                else             v = (tx < INDIM) ? headB[tx] : 0.0f;
                bias2[f * 32 + tx] = v;
            }
        }
    }
}

__device__ __forceinline__ float exp2_fast(float x) {
#if __has_builtin(__builtin_amdgcn_exp2f)
    return __builtin_amdgcn_exp2f(x);
#else
    return exp2f(x);
#endif
}

__device__ __forceinline__ unsigned pk2(float a, float b) {
    auto h2 = __builtin_amdgcn_cvt_pkrtz(a, b);   // v_cvt_pkrtz_f16_f32
    return __builtin_bit_cast(unsigned, h2);
}

// Compiler-modeled lane<32 <-> lane>=32 exchange (round-8-verified correct).
__device__ __forceinline__ void pswap(unsigned& a, unsigned& b) {
#if __has_builtin(__builtin_amdgcn_permlane32_swap)
    u32x2 r = __builtin_amdgcn_permlane32_swap(a, b, false, false);
    a = r[0];
    b = r[1];
#else
    asm("v_permlane32_swap_b32 %0, %1" : "+v"(a), "+v"(b));
    __builtin_amdgcn_sched_barrier(0);
#endif
}

// Fused BOTH-chain D -> next-layer B-fragments, stage-major (round-11).
template <bool SILU>
__device__ __forceinline__ void pack_exchange_dual(const f32x16& DA, const f32x16& DB,
                                                   BU& a0, BU& a1, BU& b0, BU& b1) {
    float sA[16], sB[16];
    if (SILU) {
        float uA[16], uB[16];
#pragma unroll
        for (int r = 0; r < 16; ++r) uA[r] = exp2_fast(-DA[r]);
#pragma unroll
        for (int r = 0; r < 16; ++r) uB[r] = exp2_fast(-DB[r]);
#pragma unroll
        for (int r = 0; r < 16; ++r) uA[r] = 1.0f + uA[r];
#pragma unroll
        for (int r = 0; r < 16; ++r) uB[r] = 1.0f + uB[r];
#pragma unroll
        for (int r = 0; r < 16; ++r) uA[r] = __builtin_amdgcn_rcpf(uA[r]);
#pragma unroll
        for (int r = 0; r < 16; ++r) uB[r] = __builtin_amdgcn_rcpf(uB[r]);
#pragma unroll
        for (int r = 0; r < 16; ++r) sA[r] = DA[r] * uA[r];
#pragma unroll
        for (int r = 0; r < 16; ++r) sB[r] = DB[r] * uB[r];
    } else {
#pragma unroll
        for (int r = 0; r < 16; ++r) { sA[r] = DA[r]; sB[r] = DB[r]; }
    }

    unsigned qa0 = pk2(sA[0],  sA[1]);
    unsigned qa1 = pk2(sA[2],  sA[3]);
    unsigned qa2 = pk2(sA[4],  sA[5]);
    unsigned qa3 = pk2(sA[6],  sA[7]);
    unsigned qa4 = pk2(sA[8],  sA[9]);
    unsigned qa5 = pk2(sA[10], sA[11]);
    unsigned qa6 = pk2(sA[12], sA[13]);
    unsigned qa7 = pk2(sA[14], sA[15]);
    unsigned qb0 = pk2(sB[0],  sB[1]);
    unsigned qb1 = pk2(sB[2],  sB[3]);
    unsigned qb2 = pk2(sB[4],  sB[5]);
    unsigned qb3 = pk2(sB[6],  sB[7]);
    unsigned qb4 = pk2(sB[8],  sB[9]);
    unsigned qb5 = pk2(sB[10], sB[11]);
    unsigned qb6 = pk2(sB[12], sB[13]);
    unsigned qb7 = pk2(sB[14], sB[15]);
    pswap(qa0, qa2); pswap(qa1, qa3); pswap(qa4, qa6); pswap(qa5, qa7);
    pswap(qb0, qb2); pswap(qb1, qb3); pswap(qb4, qb6); pswap(qb5, qb7);
    a0.u[0] = qa0; a0.u[1] = qa1; a0.u[2] = qa2; a0.u[3] = qa3;
    a1.u[0] = qa4; a1.u[1] = qa5; a1.u[2] = qa6; a1.u[3] = qa7;
    b0.u[0] = qb0; b0.u[1] = qb1; b0.u[2] = qb2; b0.u[3] = qb3;
    b1.u[0] = qb4; b1.u[1] = qb5; b1.u[2] = qb6; b1.u[3] = qb7;
}

// C-operand bias fragment from the LDS table (half-wave broadcast reads).
__device__ __forceinline__ f32x16 ld_bias(const float* sbias, int stage, int G) {
    CU c;
#pragma unroll
    for (int rq = 0; rq < 4; ++rq)
        c.q[rq] = *(const float4*)&sbias[stage * 32 + rq * 8 + G * 4];
    return c.v;
}

// A-operand fragment from LDS: lane ln reads its own 16B at stride 16
// (contiguous 1KB per frag -> conflict-free ds_read_b128).
__device__ __forceinline__ f16x8 ld_frag(const f16* sfrag, int f, int ln) {
    return *(const f16x8*)&sfrag[(f * 64 + ln) * 8];
}

template <bool GUARD>
__device__ __forceinline__ BU load_x(const float* __restrict__ x, long rb,
                                     int c, int G, int nrows) {
    BU b;
    b.u[0] = 0; b.u[1] = 0; b.u[2] = 0; b.u[3] = 0;
    const long r = rb + c;
    if (!GUARD || r < nrows) {
        const float* xp = x + r * INDIM;
        if (G == 0) {
            float2 p0 = *(const float2*)(xp + 0);
            float2 p1 = *(const float2*)(xp + 2);
            float2 p2 = *(const float2*)(xp + 4);
            float2 p3 = *(const float2*)(xp + 6);
            b.u[0] = pk2(p0.x, p0.y);
            b.u[1] = pk2(p1.x, p1.y);
            b.u[2] = pk2(p2.x, p2.y);
            b.u[3] = pk2(p3.x, p3.y);
        } else {
            float2 p4 = *(const float2*)(xp + 8);
            b.u[0] = pk2(p4.x, p4.y);
        }
    }
    return b;
}

template <bool GUARD>
__device__ __forceinline__ void store_o(float* __restrict__ out, long rb,
                                        int c, int G, int nrows, const f32x16& Dh) {
    const long r = rb + c;
    if (!GUARD || r < nrows) {
        float* op = out + r * INDIM;
        if (G == 0) {
            *(float2*)(op + 0) = make_float2(Dh[0], Dh[1]);  // f0,f1
            *(float2*)(op + 2) = make_float2(Dh[2], Dh[3]);  // f2,f3
            *(float2*)(op + 8) = make_float2(Dh[4], Dh[5]);  // f8,f9
        } else {
            *(float2*)(op + 4) = make_float2(Dh[0], Dh[1]);  // f4,f5
            *(float2*)(op + 6) = make_float2(Dh[2], Dh[3]);  // f6,f7
        }
    }
}

// ---------------------------------------------------------------------------
// Main: transposed 32x32 MFMA pipeline, dual 32-row chains per wave,
// stage-major fused silu, log2e folded (all verified).
// NEW: weight fragments live in LDS, loaded per-stage via conflict-free
// ds_read_b128 -- frees ~44 resident VGPRs (the hidden AGPR+VGPR total was
// the 3-wave/SIMD occupancy limiter).  launch_bounds (256,4) targets 4
// waves/SIMD (combined regs <= 128).
// ---------------------------------------------------------------------------
template <bool GUARD>
__global__ __launch_bounds__(256, 4) void fno_main(
    const float* __restrict__ x,
    const f16*  __restrict__ fragbuf,   // [11][64][8] f16
    const float* __restrict__ bias2,    // [6][32] f32
    float* __restrict__ out,
    int nrows) {

    __shared__ __align__(16) f16 sfrag[11 * 64 * 8];   // 11264 B
    __shared__ __align__(16) float sbias[6 * 32];      // 768 B

    {
        const int tid = threadIdx.x;
        uint4* dv = (uint4*)sfrag;
        const uint4* sv = (const uint4*)fragbuf;
#pragma unroll
        for (int i = 0; i < 3; ++i) {
            int idx = tid + i * 256;
            if (idx < 704) dv[idx] = sv[idx];
        }
        if (tid < 48) ((float4*)sbias)[tid] = ((const float4*)bias2)[tid];
    }
    __syncthreads();

    const int tid = threadIdx.x;
    const int w   = tid >> 6;
    const int ln  = tid & 63;
    const int c   = ln & 31;
    const int G   = ln >> 5;

    const long rbA = (long)blockIdx.x * 256 + (long)w * 64;
    const long rbB = rbA + 32;

    // ---- stem ----
    BU bxA = load_x<GUARD>(x, rbA, c, G, nrows);
    BU bxB = load_x<GUARD>(x, rbB, c, G, nrows);
    f32x16 cb = ld_bias(sbias, 0, G);
    f16x8 as = ld_frag(sfrag, 8, ln);
    f32x16 DA = __builtin_amdgcn_mfma_f32_32x32x16_f16(as, bxA.v, cb, 0, 0, 0);
    f32x16 DB = __builtin_amdgcn_mfma_f32_32x32x16_f16(as, bxB.v, cb, 0, 0, 0);
    cb = ld_bias(sbias, 1, G);

    BU a0, a1, b0, b1;
    pack_exchange_dual<false>(DA, DB, a0, a1, b0, b1);

    // ---- 4 fused layers, dual chains; weights read from LDS per stage ----
#pragma unroll
    for (int l = 0; l < LAYERS; ++l) {
        f16x8 w0 = ld_frag(sfrag, 2 * l, ln);
        f16x8 w1 = ld_frag(sfrag, 2 * l + 1, ln);
        f32x16 tA = __builtin_amdgcn_mfma_f32_32x32x16_f16(w0, a0.v, cb, 0, 0, 0);
        f32x16 tB = __builtin_amdgcn_mfma_f32_32x32x16_f16(w0, b0.v, cb, 0, 0, 0);
        tA = __builtin_amdgcn_mfma_f32_32x32x16_f16(w1, a1.v, tA, 0, 0, 0);
        tB = __builtin_amdgcn_mfma_f32_32x32x16_f16(w1, b1.v, tB, 0, 0, 0);
        cb = ld_bias(sbias, (l < LAYERS - 1) ? (2 + l) : 5, G);  // next stage
        pack_exchange_dual<true>(tA, tB, a0, a1, b0, b1);
    }

    // ---- head (cb holds head bias) ----
    f16x8 ah0 = ld_frag(sfrag, 9, ln);
    f16x8 ah1 = ld_frag(sfrag, 10, ln);
    f32x16 HA = __builtin_amdgcn_mfma_f32_32x32x16_f16(ah0, a0.v, cb, 0, 0, 0);
    f32x16 HB = __builtin_amdgcn_mfma_f32_32x32x16_f16(ah0, b0.v, cb, 0, 0, 0);
    HA = __builtin_amdgcn_mfma_f32_32x32x16_f16(ah1, a1.v, HA, 0, 0, 0);
    HB = __builtin_amdgcn_mfma_f32_32x32x16_f16(ah1, b1.v, HB, 0, 0, 0);

    store_o<GUARD>(out, rbA, c, G, nrows, HA);
    store_o<GUARD>(out, rbB, c, G, nrows, HB);
}

extern "C" void kernel_launch(void* const* d_in, const int* in_sizes, int n_in,
                              void* d_out, int out_size, void* d_ws, size_t ws_size,
                              hipStream_t stream) {
    const float* x      = (const float*)d_in[0];
    const float* stemW  = (const float*)d_in[1];
    const float* stemB  = (const float*)d_in[2];
    const float* fno_wr = (const float*)d_in[3];
    const float* fno_wi = (const float*)d_in[4];
    const float* projW  = (const float*)d_in[5];
    const float* projB  = (const float*)d_in[6];
    const float* headW  = (const float*)d_in[7];
    const float* headB  = (const float*)d_in[8];
    float* out = (float*)d_out;

    f16*   frag  = (f16*)((char*)d_ws + WS_FRAG_OFF);
    float* bias2 = (float*)((char*)d_ws + WS_BIAS_OFF);

    const int nrows = in_sizes[0] / INDIM;

    fno_prep<<<LAYERS, 1024, 0, stream>>>(fno_wr, fno_wi, projW, stemW, headW,
                                          stemB, projB, headB, frag, bias2);

    const int rows_per_block = 256;   // 4 waves x 2 chains x 32 rows
    const int nblk = (nrows + rows_per_block - 1) / rows_per_block;
    if (nrows % rows_per_block == 0)
        fno_main<false><<<nblk, 256, 0, stream>>>(x, frag, bias2, out, nrows);
    else
        fno_main<true><<<nblk, 256, 0, stream>>>(x, frag, bias2, out, nrows);
}

// Round 15
// 57.824 us; speedup vs baseline: 1.0509x; 1.0509x over previous
//
#include <hip/hip_runtime.h>
#include <math.h>

#define INDIM 10
#define DIM 32
#define LAYERS 4
#define MODES 17

#define LOG2E 1.4426950408889634f
#define LN2   0.6931471805599453f

// d_ws layout:
//   [0, 11264)        : frag f16 [11][64][8]  (A-operand fragments, W^T form)
//   [11264, 12032)    : bias2 f32 [6][32]     (compact per-stage bias tables)
#define WS_FRAG_OFF 0
#define WS_BIAS_OFF 11264

typedef _Float16 f16;
typedef _Float16 f16x8 __attribute__((ext_vector_type(8)));
typedef float f32x16 __attribute__((ext_vector_type(16)));
typedef unsigned u32x2 __attribute__((ext_vector_type(2)));

union BU { f16x8 v; unsigned u[4]; };
union CU { f32x16 v; float4 q[4]; };

// ---------------------------------------------------------------------------
// FUSED prep (round-13-verified): folds rfft -> mode-mix -> irfft into
// Wc[l] = M_l + proj_W[l], writes f16 A-fragments directly, block 0 packs
// stem/head fragments and bias tables.  log2e folding verified round 11.
// ---------------------------------------------------------------------------
__global__ void fno_prep(const float* __restrict__ wr,
                         const float* __restrict__ wi,
                         const float* __restrict__ projW,
                         const float* __restrict__ stemW,
                         const float* __restrict__ headW,
                         const float* __restrict__ stemB,
                         const float* __restrict__ projB,
                         const float* __restrict__ headB,
                         f16* __restrict__ frag,
                         float* __restrict__ bias2) {
    const int l  = blockIdx.x;
    const int tx = threadIdx.x;
    const int j  = tx & 31;   // output position n' (= frag column c)
    const int n  = tx >> 5;   // input position n  (= frag k)

    __shared__ float ct[32], st[32];
    if (tx < 32) {
        float ang = (2.0f * 3.14159265358979323846f / 32.0f) * (float)tx;
        ct[tx] = cosf(ang);
        st[tx] = sinf(ang);
    }
    __syncthreads();

    const float* lwr = wr + l * MODES * MODES;
    const float* lwi = wi + l * MODES * MODES;

    float acc = 0.0f;
    for (int o = 0; o < MODES; ++o) {
        float re = 0.0f, im = 0.0f;
        for (int m = 0; m < MODES; ++m) {
            int t = (m * n) & 31;
            float c = ct[t], s = st[t];
            float a = lwr[m * MODES + o];
            float b = lwi[m * MODES + o];
            re += c * a + s * b;
            im += c * b - s * a;
        }
        int t2 = (o * j) & 31;
        float f = (o == 0 || o == 16) ? 1.0f : 2.0f;
        acc += f * (re * ct[t2] - im * st[t2]);
    }
    acc = acc * (1.0f / 32.0f) + projW[(l * DIM + n) * DIM + j];

    const float wscale = (l == 0) ? LOG2E : 1.0f;
    const int kc = n >> 4;
    const int G  = (n >> 3) & 1;
    const int e  = n & 7;
    const int ln = G * 32 + j;
    frag[((l * 2 + kc) * 64 + ln) * 8 + e] = (f16)(wscale * acc);

    if (l == 0) {
        if (tx < 64) {
            const int lnn = tx;
            const int c2  = lnn & 31;
            const int G2  = lnn >> 5;
#pragma unroll
            for (int ee = 0; ee < 8; ++ee) {
                int k = 8 * G2 + ee;
                frag[(8 * 64 + lnn) * 8 + ee] =
                    (f16)(k < INDIM ? stemW[k * DIM + c2] : 0.0f);
            }
#pragma unroll
            for (int kcc = 0; kcc < 2; ++kcc)
#pragma unroll
                for (int ee = 0; ee < 8; ++ee) {
                    int k = 16 * kcc + 8 * G2 + ee;
                    frag[((9 + kcc) * 64 + lnn) * 8 + ee] =
                        (f16)(c2 < INDIM ? LN2 * headW[k * INDIM + c2] : 0.0f);
                }
        }
        if (tx < 32) {
#pragma unroll
            for (int f = 0; f < 6; ++f) {
                float v;
                if (f == 0)      v = stemB[tx];
                else if (f <= 4) v = LOG2E * projB[(f - 1) * DIM + tx];
                else             v = (tx < INDIM) ? headB[tx] : 0.0f;
                bias2[f * 32 + tx] = v;
            }
        }
    }
}

__device__ __forceinline__ float exp2_fast(float x) {
#if __has_builtin(__builtin_amdgcn_exp2f)
    return __builtin_amdgcn_exp2f(x);
#else
    return exp2f(x);
#endif
}

__device__ __forceinline__ unsigned pk2(float a, float b) {
    auto h2 = __builtin_amdgcn_cvt_pkrtz(a, b);   // v_cvt_pkrtz_f16_f32
    return __builtin_bit_cast(unsigned, h2);
}

// Compiler-modeled lane<32 <-> lane>=32 exchange (round-8-verified correct).
__device__ __forceinline__ void pswap(unsigned& a, unsigned& b) {
#if __has_builtin(__builtin_amdgcn_permlane32_swap)
    u32x2 r = __builtin_amdgcn_permlane32_swap(a, b, false, false);
    a = r[0];
    b = r[1];
#else
    asm("v_permlane32_swap_b32 %0, %1" : "+v"(a), "+v"(b));
    __builtin_amdgcn_sched_barrier(0);
#endif
}

// Single-chain D -> next-layer B-fragments, stage-major silu (exp2 form,
// round-11-verified log2e folding).
template <bool SILU>
__device__ __forceinline__ void pack_exchange(const f32x16& D, BU& b0, BU& b1) {
    float s[16];
    if (SILU) {
        float u[16];
#pragma unroll
        for (int r = 0; r < 16; ++r) u[r] = exp2_fast(-D[r]);
#pragma unroll
        for (int r = 0; r < 16; ++r) u[r] = 1.0f + u[r];
#pragma unroll
        for (int r = 0; r < 16; ++r) u[r] = __builtin_amdgcn_rcpf(u[r]);
#pragma unroll
        for (int r = 0; r < 16; ++r) s[r] = D[r] * u[r];
    } else {
#pragma unroll
        for (int r = 0; r < 16; ++r) s[r] = D[r];
    }
    unsigned q0 = pk2(s[0],  s[1]);
    unsigned q1 = pk2(s[2],  s[3]);
    unsigned q2 = pk2(s[4],  s[5]);
    unsigned q3 = pk2(s[6],  s[7]);
    unsigned q4 = pk2(s[8],  s[9]);
    unsigned q5 = pk2(s[10], s[11]);
    unsigned q6 = pk2(s[12], s[13]);
    unsigned q7 = pk2(s[14], s[15]);
    pswap(q0, q2);
    pswap(q1, q3);
    pswap(q4, q6);
    pswap(q5, q7);
    b0.u[0] = q0; b0.u[1] = q1; b0.u[2] = q2; b0.u[3] = q3;
    b1.u[0] = q4; b1.u[1] = q5; b1.u[2] = q6; b1.u[3] = q7;
}

// C-operand bias fragment from the LDS table (half-wave broadcast reads).
__device__ __forceinline__ f32x16 ld_bias(const float* sbias, int stage, int G) {
    CU c;
#pragma unroll
    for (int rq = 0; rq < 4; ++rq)
        c.q[rq] = *(const float4*)&sbias[stage * 32 + rq * 8 + G * 4];
    return c.v;
}

// A-operand fragment from LDS: lane ln reads its own 16B at stride 16
// (contiguous 1KB per frag -> conflict-free ds_read_b128; verified R14).
__device__ __forceinline__ f16x8 ld_frag(const f16* sfrag, int f, int ln) {
    return *(const f16x8*)&sfrag[(f * 64 + ln) * 8];
}

template <bool GUARD>
__device__ __forceinline__ BU load_x(const float* __restrict__ x, long rb,
                                     int c, int G, int nrows) {
    BU b;
    b.u[0] = 0; b.u[1] = 0; b.u[2] = 0; b.u[3] = 0;
    const long r = rb + c;
    if (!GUARD || r < nrows) {
        const float* xp = x + r * INDIM;
        if (G == 0) {
            float2 p0 = *(const float2*)(xp + 0);
            float2 p1 = *(const float2*)(xp + 2);
            float2 p2 = *(const float2*)(xp + 4);
            float2 p3 = *(const float2*)(xp + 6);
            b.u[0] = pk2(p0.x, p0.y);
            b.u[1] = pk2(p1.x, p1.y);
            b.u[2] = pk2(p2.x, p2.y);
            b.u[3] = pk2(p3.x, p3.y);
        } else {
            float2 p4 = *(const float2*)(xp + 8);
            b.u[0] = pk2(p4.x, p4.y);
        }
    }
    return b;
}

template <bool GUARD>
__device__ __forceinline__ void store_o(float* __restrict__ out, long rb,
                                        int c, int G, int nrows, const f32x16& Dh) {
    const long r = rb + c;
    if (!GUARD || r < nrows) {
        float* op = out + r * INDIM;
        if (G == 0) {
            *(float2*)(op + 0) = make_float2(Dh[0], Dh[1]);  // f0,f1
            *(float2*)(op + 2) = make_float2(Dh[2], Dh[3]);  // f2,f3
            *(float2*)(op + 8) = make_float2(Dh[4], Dh[5]);  // f8,f9
        } else {
            *(float2*)(op + 4) = make_float2(Dh[0], Dh[1]);  // f4,f5
            *(float2*)(op + 6) = make_float2(Dh[2], Dh[3]);  // f6,f7
        }
    }
}

// ---------------------------------------------------------------------------
// Main: transposed 32x32 MFMA pipeline, SINGLE 32-row chain per wave.
// R8's dual-chain ILP was worth only ~4% but doubled register state,
// capping residency at ~4.5 waves/SIMD (R14).  This round trades that ILP
// back for TLP: half the per-wave state (one f32x16 acc, one B-frag pair),
// weights in LDS (R14-verified conflict-free), bias loaded at-use (R13
// showed prefetch null; at-use shortens cb's live range).
// __launch_bounds__(256,6): <=85 combined regs -> 6 waves/SIMD target.
// ---------------------------------------------------------------------------
template <bool GUARD>
__global__ __launch_bounds__(256, 6) void fno_main(
    const float* __restrict__ x,
    const f16*  __restrict__ fragbuf,   // [11][64][8] f16
    const float* __restrict__ bias2,    // [6][32] f32
    float* __restrict__ out,
    int nrows) {

    __shared__ __align__(16) f16 sfrag[11 * 64 * 8];   // 11264 B
    __shared__ __align__(16) float sbias[6 * 32];      // 768 B

    {
        const int tid = threadIdx.x;
        uint4* dv = (uint4*)sfrag;
        const uint4* sv = (const uint4*)fragbuf;
#pragma unroll
        for (int i = 0; i < 3; ++i) {
            int idx = tid + i * 256;
            if (idx < 704) dv[idx] = sv[idx];
        }
        if (tid < 48) ((float4*)sbias)[tid] = ((const float4*)bias2)[tid];
    }
    __syncthreads();

    const int tid = threadIdx.x;
    const int w   = tid >> 6;
    const int ln  = tid & 63;
    const int c   = ln & 31;
    const int G   = ln >> 5;

    const long rb = (long)blockIdx.x * 128 + (long)w * 32;

    // ---- stem ----
    BU bx = load_x<GUARD>(x, rb, c, G, nrows);
    f16x8 as = ld_frag(sfrag, 8, ln);
    f32x16 cb = ld_bias(sbias, 0, G);
    f32x16 D = __builtin_amdgcn_mfma_f32_32x32x16_f16(as, bx.v, cb, 0, 0, 0);

    BU b0, b1;
    pack_exchange<false>(D, b0, b1);

    // ---- 4 fused layers; weights + bias read from LDS at use ----
#pragma unroll
    for (int l = 0; l < LAYERS; ++l) {
        f16x8 w0 = ld_frag(sfrag, 2 * l, ln);
        f16x8 w1 = ld_frag(sfrag, 2 * l + 1, ln);
        cb = ld_bias(sbias, 1 + l, G);
        f32x16 t = __builtin_amdgcn_mfma_f32_32x32x16_f16(w0, b0.v, cb, 0, 0, 0);
        t = __builtin_amdgcn_mfma_f32_32x32x16_f16(w1, b1.v, t, 0, 0, 0);
        pack_exchange<true>(t, b0, b1);
    }

    // ---- head ----
    f16x8 ah0 = ld_frag(sfrag, 9, ln);
    f16x8 ah1 = ld_frag(sfrag, 10, ln);
    cb = ld_bias(sbias, 5, G);
    f32x16 H = __builtin_amdgcn_mfma_f32_32x32x16_f16(ah0, b0.v, cb, 0, 0, 0);
    H = __builtin_amdgcn_mfma_f32_32x32x16_f16(ah1, b1.v, H, 0, 0, 0);

    store_o<GUARD>(out, rb, c, G, nrows, H);
}

extern "C" void kernel_launch(void* const* d_in, const int* in_sizes, int n_in,
                              void* d_out, int out_size, void* d_ws, size_t ws_size,
                              hipStream_t stream) {
    const float* x      = (const float*)d_in[0];
    const float* stemW  = (const float*)d_in[1];
    const float* stemB  = (const float*)d_in[2];
    const float* fno_wr = (const float*)d_in[3];
    const float* fno_wi = (const float*)d_in[4];
    const float* projW  = (const float*)d_in[5];
    const float* projB  = (const float*)d_in[6];
    const float* headW  = (const float*)d_in[7];
    const float* headB  = (const float*)d_in[8];
    float* out = (float*)d_out;

    f16*   frag  = (f16*)((char*)d_ws + WS_FRAG_OFF);
    float* bias2 = (float*)((char*)d_ws + WS_BIAS_OFF);

    const int nrows = in_sizes[0] / INDIM;

    fno_prep<<<LAYERS, 1024, 0, stream>>>(fno_wr, fno_wi, projW, stemW, headW,
                                          stemB, projB, headB, frag, bias2);

    const int rows_per_block = 128;   // 4 waves x 1 chain x 32 rows
    const int nblk = (nrows + rows_per_block - 1) / rows_per_block;
    if (nrows % rows_per_block == 0)
        fno_main<false><<<nblk, 256, 0, stream>>>(x, frag, bias2, out, nrows);
    else
        fno_main<true><<<nblk, 256, 0, stream>>>(x, frag, bias2, out, nrows);
}

// Round 16
// 50.288 us; speedup vs baseline: 1.2084x; 1.1498x over previous
//
#include <hip/hip_runtime.h>
#include <math.h>

#define INDIM 10
#define DIM 32
#define LAYERS 4
#define MODES 17

#define LOG2E 1.4426950408889634f
#define LN2   0.6931471805599453f

// d_ws layout:
//   [0, 11264)        : frag f16 [11][64][8]  (A-operand fragments, W^T form)
//   [11264, 12032)    : bias2 f32 [6][32]     (compact per-stage bias tables)
#define WS_FRAG_OFF 0
#define WS_BIAS_OFF 11264

typedef _Float16 f16;
typedef _Float16 f16x8 __attribute__((ext_vector_type(8)));
typedef float f32x16 __attribute__((ext_vector_type(16)));
typedef unsigned u32x2 __attribute__((ext_vector_type(2)));

union BU { f16x8 v; unsigned u[4]; };
union CU { f32x16 v; float4 q[4]; };

// ---------------------------------------------------------------------------
// FUSED prep, now 2-phase to kill the 32x redundant mode-sum:
//   phase 1: 544 threads compute y_o(n) = sum_m e^{-2pi i mn/32} w[m][o]
//            ONCE into LDS (was recomputed by all 32 j-threads).
//   phase 2: each (n,j) thread does the 17-term o-sum from LDS broadcast.
// Same arithmetic order as rounds 1-15 (m-sum then o-sum) -> identical
// results.  Fragment/bias packing identical to round-13-verified version.
// ---------------------------------------------------------------------------
__global__ void fno_prep(const float* __restrict__ wr,
                         const float* __restrict__ wi,
                         const float* __restrict__ projW,
                         const float* __restrict__ stemW,
                         const float* __restrict__ headW,
                         const float* __restrict__ stemB,
                         const float* __restrict__ projB,
                         const float* __restrict__ headB,
                         f16* __restrict__ frag,
                         float* __restrict__ bias2) {
    const int l  = blockIdx.x;
    const int tx = threadIdx.x;
    const int j  = tx & 31;   // output position n' (= frag column c)
    const int n  = tx >> 5;   // input position n  (= frag k)

    __shared__ float ct[32], st[32];
    __shared__ float sre[MODES][32], sim[MODES][32];
    if (tx < 32) {
        float ang = (2.0f * 3.14159265358979323846f / 32.0f) * (float)tx;
        ct[tx] = cosf(ang);
        st[tx] = sinf(ang);
    }
    __syncthreads();

    const float* lwr = wr + l * MODES * MODES;
    const float* lwi = wi + l * MODES * MODES;

    // ---- phase 1: y_o(n) once per (o,n) ----
    if (tx < MODES * 32) {
        const int o  = tx >> 5;
        const int nn = tx & 31;
        float re = 0.0f, im = 0.0f;
        for (int m = 0; m < MODES; ++m) {
            int t = (m * nn) & 31;
            float c = ct[t], s = st[t];
            float a = lwr[m * MODES + o];
            float b = lwi[m * MODES + o];
            re += c * a + s * b;
            im += c * b - s * a;
        }
        sre[o][nn] = re;
        sim[o][nn] = im;
    }
    __syncthreads();

    // ---- phase 2: o-sum from LDS (sre/sim broadcast across j-lanes) ----
    float acc = 0.0f;
    for (int o = 0; o < MODES; ++o) {
        int t2 = (o * j) & 31;
        float f = (o == 0 || o == 16) ? 1.0f : 2.0f;
        acc += f * (sre[o][n] * ct[t2] - sim[o][n] * st[t2]);
    }
    acc = acc * (1.0f / 32.0f) + projW[(l * DIM + n) * DIM + j];

    const float wscale = (l == 0) ? LOG2E : 1.0f;
    const int kc = n >> 4;
    const int G  = (n >> 3) & 1;
    const int e  = n & 7;
    const int ln = G * 32 + j;
    frag[((l * 2 + kc) * 64 + ln) * 8 + e] = (f16)(wscale * acc);

    if (l == 0) {
        if (tx < 64) {
            const int lnn = tx;
            const int c2  = lnn & 31;
            const int G2  = lnn >> 5;
#pragma unroll
            for (int ee = 0; ee < 8; ++ee) {
                int k = 8 * G2 + ee;
                frag[(8 * 64 + lnn) * 8 + ee] =
                    (f16)(k < INDIM ? stemW[k * DIM + c2] : 0.0f);
            }
#pragma unroll
            for (int kcc = 0; kcc < 2; ++kcc)
#pragma unroll
                for (int ee = 0; ee < 8; ++ee) {
                    int k = 16 * kcc + 8 * G2 + ee;
                    frag[((9 + kcc) * 64 + lnn) * 8 + ee] =
                        (f16)(c2 < INDIM ? LN2 * headW[k * INDIM + c2] : 0.0f);
                }
        }
        if (tx < 32) {
#pragma unroll
            for (int f = 0; f < 6; ++f) {
                float v;
                if (f == 0)      v = stemB[tx];
                else if (f <= 4) v = LOG2E * projB[(f - 1) * DIM + tx];
                else             v = (tx < INDIM) ? headB[tx] : 0.0f;
                bias2[f * 32 + tx] = v;
            }
        }
    }
}

__device__ __forceinline__ float exp2_fast(float x) {
#if __has_builtin(__builtin_amdgcn_exp2f)
    return __builtin_amdgcn_exp2f(x);
#else
    return exp2f(x);
#endif
}

__device__ __forceinline__ unsigned pk2(float a, float b) {
    auto h2 = __builtin_amdgcn_cvt_pkrtz(a, b);   // v_cvt_pkrtz_f16_f32
    return __builtin_bit_cast(unsigned, h2);
}

// Compiler-modeled lane<32 <-> lane>=32 exchange (round-8-verified correct).
__device__ __forceinline__ void pswap(unsigned& a, unsigned& b) {
#if __has_builtin(__builtin_amdgcn_permlane32_swap)
    u32x2 r = __builtin_amdgcn_permlane32_swap(a, b, false, false);
    a = r[0];
    b = r[1];
#else
    asm("v_permlane32_swap_b32 %0, %1" : "+v"(a), "+v"(b));
    __builtin_amdgcn_sched_barrier(0);
#endif
}

// Single-chain D -> next-layer B-fragments.  Silu in TWO half-blocks of 8
// (8 exp2 -> 8 add -> 8 rcp -> 8 mul): still 7 independent ops between any
// dependent pair (trans pipe stays fed), but peak live regs drop by 8 so
// the 64-reg class (8 waves/SIMD) is reachable.
template <bool SILU>
__device__ __forceinline__ void pack_exchange(const f32x16& D, BU& b0, BU& b1) {
    unsigned q[8];
#pragma unroll
    for (int h = 0; h < 2; ++h) {
        float u[8];
        if (SILU) {
#pragma unroll
            for (int r = 0; r < 8; ++r) u[r] = exp2_fast(-D[8 * h + r]);
#pragma unroll
            for (int r = 0; r < 8; ++r) u[r] = 1.0f + u[r];
#pragma unroll
            for (int r = 0; r < 8; ++r) u[r] = __builtin_amdgcn_rcpf(u[r]);
#pragma unroll
            for (int r = 0; r < 8; ++r) u[r] = D[8 * h + r] * u[r];
        } else {
#pragma unroll
            for (int r = 0; r < 8; ++r) u[r] = D[8 * h + r];
        }
        q[4 * h + 0] = pk2(u[0], u[1]);
        q[4 * h + 1] = pk2(u[2], u[3]);
        q[4 * h + 2] = pk2(u[4], u[5]);
        q[4 * h + 3] = pk2(u[6], u[7]);
    }
    pswap(q[0], q[2]);
    pswap(q[1], q[3]);
    pswap(q[4], q[6]);
    pswap(q[5], q[7]);
    b0.u[0] = q[0]; b0.u[1] = q[1]; b0.u[2] = q[2]; b0.u[3] = q[3];
    b1.u[0] = q[4]; b1.u[1] = q[5]; b1.u[2] = q[6]; b1.u[3] = q[7];
}

// C-operand bias fragment from the LDS table (half-wave broadcast reads).
__device__ __forceinline__ f32x16 ld_bias(const float* sbias, int stage, int G) {
    CU c;
#pragma unroll
    for (int rq = 0; rq < 4; ++rq)
        c.q[rq] = *(const float4*)&sbias[stage * 32 + rq * 8 + G * 4];
    return c.v;
}

// A-operand fragment from LDS: lane ln reads its own 16B at stride 16
// (contiguous 1KB per frag -> conflict-free ds_read_b128; verified R14).
__device__ __forceinline__ f16x8 ld_frag(const f16* sfrag, int f, int ln) {
    return *(const f16x8*)&sfrag[(f * 64 + ln) * 8];
}

template <bool GUARD>
__device__ __forceinline__ BU load_x(const float* __restrict__ x, long rb,
                                     int c, int G, int nrows) {
    BU b;
    b.u[0] = 0; b.u[1] = 0; b.u[2] = 0; b.u[3] = 0;
    const long r = rb + c;
    if (!GUARD || r < nrows) {
        const float* xp = x + r * INDIM;
        if (G == 0) {
            float2 p0 = *(const float2*)(xp + 0);
            float2 p1 = *(const float2*)(xp + 2);
            float2 p2 = *(const float2*)(xp + 4);
            float2 p3 = *(const float2*)(xp + 6);
            b.u[0] = pk2(p0.x, p0.y);
            b.u[1] = pk2(p1.x, p1.y);
            b.u[2] = pk2(p2.x, p2.y);
            b.u[3] = pk2(p3.x, p3.y);
        } else {
            float2 p4 = *(const float2*)(xp + 8);
            b.u[0] = pk2(p4.x, p4.y);
        }
    }
    return b;
}

template <bool GUARD>
__device__ __forceinline__ void store_o(float* __restrict__ out, long rb,
                                        int c, int G, int nrows, const f32x16& Dh) {
    const long r = rb + c;
    if (!GUARD || r < nrows) {
        float* op = out + r * INDIM;
        if (G == 0) {
            *(float2*)(op + 0) = make_float2(Dh[0], Dh[1]);  // f0,f1
            *(float2*)(op + 2) = make_float2(Dh[2], Dh[3]);  // f2,f3
            *(float2*)(op + 8) = make_float2(Dh[4], Dh[5]);  // f8,f9
        } else {
            *(float2*)(op + 4) = make_float2(Dh[0], Dh[1]);  // f4,f5
            *(float2*)(op + 6) = make_float2(Dh[2], Dh[3]);  // f6,f7
        }
    }
}

// ---------------------------------------------------------------------------
// Main: transposed 32x32 MFMA pipeline, SINGLE 32-row chain per wave
// (R15-verified), weights in LDS (R14-verified), bias at-use (R13).
// NEW: __launch_bounds__(256,8) -- the half-block silu cut peak live regs
// so the 64-combined-reg class (8 waves/SIMD) should be reachable; R15's
// remaining 34% idle was dependency latency at 5.2 waves/SIMD.
// ---------------------------------------------------------------------------
template <bool GUARD>
__global__ __launch_bounds__(256, 8) void fno_main(
    const float* __restrict__ x,
    const f16*  __restrict__ fragbuf,   // [11][64][8] f16
    const float* __restrict__ bias2,    // [6][32] f32
    float* __restrict__ out,
    int nrows) {

    __shared__ __align__(16) f16 sfrag[11 * 64 * 8];   // 11264 B
    __shared__ __align__(16) float sbias[6 * 32];      // 768 B

    {
        const int tid = threadIdx.x;
        uint4* dv = (uint4*)sfrag;
        const uint4* sv = (const uint4*)fragbuf;
#pragma unroll
        for (int i = 0; i < 3; ++i) {
            int idx = tid + i * 256;
            if (idx < 704) dv[idx] = sv[idx];
        }
        if (tid < 48) ((float4*)sbias)[tid] = ((const float4*)bias2)[tid];
    }
    __syncthreads();

    const int tid = threadIdx.x;
    const int w   = tid >> 6;
    const int ln  = tid & 63;
    const int c   = ln & 31;
    const int G   = ln >> 5;

    const long rb = (long)blockIdx.x * 128 + (long)w * 32;

    // ---- stem ----
    BU bx = load_x<GUARD>(x, rb, c, G, nrows);
    f16x8 as = ld_frag(sfrag, 8, ln);
    f32x16 cb = ld_bias(sbias, 0, G);
    f32x16 D = __builtin_amdgcn_mfma_f32_32x32x16_f16(as, bx.v, cb, 0, 0, 0);

    BU b0, b1;
    pack_exchange<false>(D, b0, b1);

    // ---- 4 fused layers; weights + bias read from LDS at use ----
#pragma unroll
    for (int l = 0; l < LAYERS; ++l) {
        f16x8 w0 = ld_frag(sfrag, 2 * l, ln);
        f16x8 w1 = ld_frag(sfrag, 2 * l + 1, ln);
        cb = ld_bias(sbias, 1 + l, G);
        f32x16 t = __builtin_amdgcn_mfma_f32_32x32x16_f16(w0, b0.v, cb, 0, 0, 0);
        t = __builtin_amdgcn_mfma_f32_32x32x16_f16(w1, b1.v, t, 0, 0, 0);
        pack_exchange<true>(t, b0, b1);
    }

    // ---- head ----
    f16x8 ah0 = ld_frag(sfrag, 9, ln);
    f16x8 ah1 = ld_frag(sfrag, 10, ln);
    cb = ld_bias(sbias, 5, G);
    f32x16 H = __builtin_amdgcn_mfma_f32_32x32x16_f16(ah0, b0.v, cb, 0, 0, 0);
    H = __builtin_amdgcn_mfma_f32_32x32x16_f16(ah1, b1.v, H, 0, 0, 0);

    store_o<GUARD>(out, rb, c, G, nrows, H);
}

extern "C" void kernel_launch(void* const* d_in, const int* in_sizes, int n_in,
                              void* d_out, int out_size, void* d_ws, size_t ws_size,
                              hipStream_t stream) {
    const float* x      = (const float*)d_in[0];
    const float* stemW  = (const float*)d_in[1];
    const float* stemB  = (const float*)d_in[2];
    const float* fno_wr = (const float*)d_in[3];
    const float* fno_wi = (const float*)d_in[4];
    const float* projW  = (const float*)d_in[5];
    const float* projB  = (const float*)d_in[6];
    const float* headW  = (const float*)d_in[7];
    const float* headB  = (const float*)d_in[8];
    float* out = (float*)d_out;

    f16*   frag  = (f16*)((char*)d_ws + WS_FRAG_OFF);
    float* bias2 = (float*)((char*)d_ws + WS_BIAS_OFF);

    const int nrows = in_sizes[0] / INDIM;

    fno_prep<<<LAYERS, 1024, 0, stream>>>(fno_wr, fno_wi, projW, stemW, headW,
                                          stemB, projB, headB, frag, bias2);

    const int rows_per_block = 128;   // 4 waves x 1 chain x 32 rows
    const int nblk = (nrows + rows_per_block - 1) / rows_per_block;
    if (nrows % rows_per_block == 0)
        fno_main<false><<<nblk, 256, 0, stream>>>(x, frag, bias2, out, nrows);
    else
        fno_main<true><<<nblk, 256, 0, stream>>>(x, frag, bias2, out, nrows);
}